// Round 9
// baseline (450.142 us; speedup 1.0000x reference)
//
#include <hip/hip_runtime.h>
#include <hip/hip_bf16.h>

// TreeLSTM on MI355X — round 21: two chains per block (real occupancy fix).
// R20 post-mortem: grid=256 blocks on 256 CUs -> halving LDS could never give
// a second resident block; occupancy stayed 22%. Fix: pack TWO independent
// (layer,tree) chains into one 1024-thread block (waves 0-7 = chain 0,
// waves 8-15 = chain 1), each with its own 69-KB LDS half (138 KB total).
// Every SIMD now hosts 4 waves with independent work -> 2x latency hiding,
// delivered through block shape instead of grid shape.
// Per-chain structure is R20's verified slim layout (d7 h/c via global,
// flat heap rows 0..126, leaf dbuf overlaying the d6 region). 2 dispatches.

#define TS 511
#define NT 128
#define NN (NT * TS)   // 65408

typedef __attribute__((ext_vector_type(8))) short short8;
typedef __attribute__((ext_vector_type(4))) float floatx4;

#define MFMA_B16 __builtin_amdgcn_mfma_f32_16x16x32_bf16

// LDS-only barrier: LDS writes visible, global loads NOT drained.
#define BARLDS() do { \
    asm volatile("s_waitcnt lgkmcnt(0)" ::: "memory"); \
    __builtin_amdgcn_s_barrier(); \
    asm volatile("" ::: "memory"); \
} while (0)

__device__ __forceinline__ unsigned short f2b(float f) {
    return __builtin_bit_cast(unsigned short, __float2bfloat16(f));
}
__device__ __forceinline__ float b2f_u(unsigned short u) {
    unsigned v = (unsigned)u << 16;
    return __builtin_bit_cast(float, v);
}
__device__ __forceinline__ float rcp_(float x) { return __builtin_amdgcn_rcpf(x); }
__device__ __forceinline__ float sig_(float x) { return rcp_(1.0f + __expf(-x)); }
__device__ __forceinline__ float tanh_(float x) {
    float a = fabsf(x);
    float t = __expf(-2.0f * a);
    return copysignf((1.0f - t) * rcp_(1.0f + t), x);
}

// ---------------- weight packing + x conversion (unchanged) ----------------
__global__ void pack_b(const float* __restrict__ Wiou, const float* __restrict__ biou,
                       const float* __restrict__ Uiou, const float* __restrict__ Wf,
                       const float* __restrict__ bfv, const float* __restrict__ Uf,
                       const float* __restrict__ feat,
                       unsigned short* __restrict__ BgU, unsigned short* __restrict__ BgX,
                       float* __restrict__ bp5, unsigned short* __restrict__ xb) {
    int tid = blockIdx.x * 256 + threadIdx.x;   // 0..1308671
    if (tid < 1280) {
        int l = tid / 640, r = tid % 640, g = r >> 7, o = r & 127;
        bp5[tid] = (g < 3) ? biou[l * 384 + r] : bfv[l * 128 + o];
    }
    if (tid < 131072) {
        int l = tid >> 16, r = tid & 65535, col = r >> 7, kp = r & 127;
        float v = (col < 384) ? Uiou[(l * 384 + col) * 128 + kp]
                              : Uf[(l * 128 + (col - 384)) * 128 + kp];
        BgU[((size_t)(l * 512 + col)) * 128 + kp] = f2b(v);
    } else if (tid < 262144) {
        int e2 = tid - 131072;
        int l = e2 >> 16, r = e2 & 65535, col = r >> 7, kp = r & 127;
        float v = (col < 384) ? Wiou[(l * 384 + col) * 128 + kp]
                              : Wf[(l * 128 + (col - 384)) * 128 + kp];
        BgX[((size_t)(l * 512 + col)) * 128 + kp] = f2b(v);
    } else {
        int e = tid - 262144;                  // < 1046528, 8 elems each
        size_t base = (size_t)e * 8;
        float4 v0 = *(const float4*)(feat + base);
        float4 v1 = *(const float4*)(feat + base + 4);
        short8 r;
        r[0] = (short)f2b(v0.x); r[1] = (short)f2b(v0.y);
        r[2] = (short)f2b(v0.z); r[3] = (short)f2b(v0.w);
        r[4] = (short)f2b(v1.x); r[5] = (short)f2b(v1.y);
        r[6] = (short)f2b(v1.z); r[7] = (short)f2b(v1.w);
        *(short8*)(xb + base) = r;
    }
}

// ---------------- fused forest: 2 chains/block, 138 KB LDS ----------------
// Per chain (stride 34560 hw): flat heap rows 0..126: h @ row*136,
//   c @ HC0 + row*136 (HC0=17272). Leaf dbuf overlays rows 63..126 during the
//   leaf/d7 phase. d7 h/c -> global hb7/cb7[((l*128+tree)*128+di)*128+o].
__global__ __launch_bounds__(1024) void forest(
        const unsigned short* __restrict__ xb16, const unsigned short* __restrict__ BgU,
        const unsigned short* __restrict__ BgX, const float* __restrict__ bp5,
        unsigned short* __restrict__ hb7, unsigned short* __restrict__ cb7,
        float* __restrict__ out) {
    __shared__ __align__(16) unsigned short Sall[69120];
    const int HC0 = 17272;

    const int tid = threadIdx.x;
    const int chain = tid >> 9;                 // 0,1
    const int tid2 = tid & 511;
    const int gid = blockIdx.x * 2 + chain;     // 0..255
    const int l = gid >> 7, tree = gid & 127;
    const int lane = tid & 63, w = tid2 >> 6;   // wave-in-chain 0..7
    const int quad = lane >> 4, l15 = lane & 15;
    const int o = w * 16 + l15;
    unsigned short* S = Sall + chain * 34560;
    const unsigned short* xb = xb16 + (size_t)tree * TS * 128;
    unsigned short* lh = hb7 + ((size_t)(l * 128 + tree)) * 128 * 128;
    unsigned short* lc = cb7 + ((size_t)(l * 128 + tree)) * 128 * 128;
    const unsigned short* BU = BgU + (size_t)l * 512 * 128;
    const unsigned short* BX = BgX + (size_t)l * 512 * 128;

    // resident B fragments: gates i,o,u,f (f0/f1 share Wf and Uf cols)
    short8 bU[4][4], bX[4][4];
#pragma unroll
    for (int g = 0; g < 4; g++) {
        const size_t cb = (size_t)(g * 128 + o) * 128;
#pragma unroll
        for (int kbl = 0; kbl < 4; kbl++) {
            bU[g][kbl] = *(const short8*)(BU + cb + kbl * 32 + quad * 8);
            bX[g][kbl] = *(const short8*)(BX + cb + kbl * 32 + quad * 8);
        }
    }
    float bb[5];
#pragma unroll
    for (int g = 0; g < 5; g++) bb[g] = bp5[l * 640 + g * 128 + o];

    auto ldx = [&](int heap, int kbl) -> short8 {
        return *(const short8*)(xb + (size_t)heap * 128 + kbl * 32 + quad * 8);
    };

    // 16-row leaf tile: x-only gates -> leaf buffer rows (h- and c-space)
    auto ltile = [&](int heapA, int selfR) {
        floatx4 ai = (floatx4){0.f, 0.f, 0.f, 0.f};
        floatx4 ao = ai, au = ai;
#pragma unroll
        for (int kbl = 0; kbl < 4; kbl++) {
            short8 ax = ldx(heapA, kbl);
            ai = MFMA_B16(ax, bX[0][kbl], ai, 0, 0, 0);
            ao = MFMA_B16(ax, bX[1][kbl], ao, 0, 0, 0);
            au = MFMA_B16(ax, bX[2][kbl], au, 0, 0, 0);
        }
#pragma unroll
        for (int r = 0; r < 4; r++) {
            int idx = quad * 4 + r;
            float iv = sig_(ai[r] + bb[0]);
            float ov = sig_(ao[r] + bb[1]);
            float uv = tanh_(au[r] + bb[2]);
            float cn = iv * uv;
            float hn = ov * tanh_(cn);
            S[(selfR + idx) * 136 + o] = f2b(hn);
            S[HC0 + (selfR + idx) * 136 + o] = f2b(cn);
        }
    };

    // d7 tile t: children from leaf buffer b (LDS); h/c -> GLOBAL.
    auto d7g = [&](int t, int b) {
        const int chAh = 63 + b * 32 + 2 * l15;
        floatx4 ai = (floatx4){0.f, 0.f, 0.f, 0.f};
        floatx4 ao = ai, au = ai, awx = ai, af0 = ai, af1 = ai;
#pragma unroll
        for (int kbl = 0; kbl < 4; kbl++) {
            short8 h0 = *(const short8*)&S[chAh * 136 + kbl * 32 + quad * 8];
            short8 h1 = *(const short8*)&S[(chAh + 1) * 136 + kbl * 32 + quad * 8];
            short8 ax = ldx(127 + 16 * t + l15, kbl);
            ai = MFMA_B16(h0, bU[0][kbl], ai, 0, 0, 0);
            ai = MFMA_B16(h1, bU[0][kbl], ai, 0, 0, 0);
            ao = MFMA_B16(h0, bU[1][kbl], ao, 0, 0, 0);
            ao = MFMA_B16(h1, bU[1][kbl], ao, 0, 0, 0);
            au = MFMA_B16(h0, bU[2][kbl], au, 0, 0, 0);
            au = MFMA_B16(h1, bU[2][kbl], au, 0, 0, 0);
            af0 = MFMA_B16(h0, bU[3][kbl], af0, 0, 0, 0);
            af1 = MFMA_B16(h1, bU[3][kbl], af1, 0, 0, 0);
            ai = MFMA_B16(ax, bX[0][kbl], ai, 0, 0, 0);
            ao = MFMA_B16(ax, bX[1][kbl], ao, 0, 0, 0);
            au = MFMA_B16(ax, bX[2][kbl], au, 0, 0, 0);
            awx = MFMA_B16(ax, bX[3][kbl], awx, 0, 0, 0);
        }
#pragma unroll
        for (int r = 0; r < 4; r++) {
            int idx = quad * 4 + r;
            float iv = sig_(ai[r] + bb[0]);
            float ov = sig_(ao[r] + bb[1]);
            float uv = tanh_(au[r] + bb[2]);
            float f0 = sig_(awx[r] + af0[r] + bb[3]);
            float f1 = sig_(awx[r] + af1[r] + bb[4]);
            float c0 = b2f_u(S[HC0 + (63 + b * 32 + 2 * idx) * 136 + o]);
            float c1 = b2f_u(S[HC0 + (63 + b * 32 + 2 * idx + 1) * 136 + o]);
            float cn = iv * uv + f0 * c0 + f1 * c1;
            float hn = ov * tanh_(cn);
            size_t gi = (size_t)(t * 16 + idx) * 128 + o;
            lh[gi] = f2b(hn);
            lc[gi] = f2b(cn);
        }
    };

    // d6 tile j: children (d7) from GLOBAL; h/c -> LDS.
    auto d6g = [&](int j) {
        const int di0 = 32 * j + 2 * l15;
        floatx4 ai = (floatx4){0.f, 0.f, 0.f, 0.f};
        floatx4 ao = ai, au = ai, awx = ai, af0 = ai, af1 = ai;
#pragma unroll
        for (int kbl = 0; kbl < 4; kbl++) {
            short8 h0 = *(const short8*)(lh + (size_t)di0 * 128 + kbl * 32 + quad * 8);
            short8 h1 = *(const short8*)(lh + (size_t)(di0 + 1) * 128 + kbl * 32 + quad * 8);
            short8 ax = ldx(63 + 16 * j + l15, kbl);
            ai = MFMA_B16(h0, bU[0][kbl], ai, 0, 0, 0);
            ai = MFMA_B16(h1, bU[0][kbl], ai, 0, 0, 0);
            ao = MFMA_B16(h0, bU[1][kbl], ao, 0, 0, 0);
            ao = MFMA_B16(h1, bU[1][kbl], ao, 0, 0, 0);
            au = MFMA_B16(h0, bU[2][kbl], au, 0, 0, 0);
            au = MFMA_B16(h1, bU[2][kbl], au, 0, 0, 0);
            af0 = MFMA_B16(h0, bU[3][kbl], af0, 0, 0, 0);
            af1 = MFMA_B16(h1, bU[3][kbl], af1, 0, 0, 0);
            ai = MFMA_B16(ax, bX[0][kbl], ai, 0, 0, 0);
            ao = MFMA_B16(ax, bX[1][kbl], ao, 0, 0, 0);
            au = MFMA_B16(ax, bX[2][kbl], au, 0, 0, 0);
            awx = MFMA_B16(ax, bX[3][kbl], awx, 0, 0, 0);
        }
#pragma unroll
        for (int r = 0; r < 4; r++) {
            int idx = quad * 4 + r;
            int node = 63 + 16 * j + idx;
            int dic = 32 * j + 2 * idx;
            float iv = sig_(ai[r] + bb[0]);
            float ov = sig_(ao[r] + bb[1]);
            float uv = tanh_(au[r] + bb[2]);
            float f0 = sig_(awx[r] + af0[r] + bb[3]);
            float f1 = sig_(awx[r] + af1[r] + bb[4]);
            float c0 = b2f_u(lc[(size_t)dic * 128 + o]);
            float c1 = b2f_u(lc[(size_t)(dic + 1) * 128 + o]);
            float cn = iv * uv + f0 * c0 + f1 * c1;
            float hn = ov * tanh_(cn);
            S[node * 136 + o] = f2b(hn);
            S[HC0 + node * 136 + o] = f2b(cn);
        }
    };

    // internal tile with LDS children (flat heap): nodes heap base+idx (idx<nv)
    auto itile_l = [&](int base, int nv, bool isRoot) {
        const int rl = (l15 < nv) ? l15 : nv - 1;
        const int nA = base + rl;
        const int ch0 = 2 * nA + 1;
        floatx4 ai = (floatx4){0.f, 0.f, 0.f, 0.f};
        floatx4 ao = ai, au = ai, awx = ai, af0 = ai, af1 = ai;
#pragma unroll
        for (int kbl = 0; kbl < 4; kbl++) {
            short8 h0 = *(const short8*)&S[ch0 * 136 + kbl * 32 + quad * 8];
            short8 h1 = *(const short8*)&S[(ch0 + 1) * 136 + kbl * 32 + quad * 8];
            short8 ax = ldx(nA, kbl);
            ai = MFMA_B16(h0, bU[0][kbl], ai, 0, 0, 0);
            ai = MFMA_B16(h1, bU[0][kbl], ai, 0, 0, 0);
            ao = MFMA_B16(h0, bU[1][kbl], ao, 0, 0, 0);
            ao = MFMA_B16(h1, bU[1][kbl], ao, 0, 0, 0);
            au = MFMA_B16(h0, bU[2][kbl], au, 0, 0, 0);
            au = MFMA_B16(h1, bU[2][kbl], au, 0, 0, 0);
            af0 = MFMA_B16(h0, bU[3][kbl], af0, 0, 0, 0);
            af1 = MFMA_B16(h1, bU[3][kbl], af1, 0, 0, 0);
            ai = MFMA_B16(ax, bX[0][kbl], ai, 0, 0, 0);
            ao = MFMA_B16(ax, bX[1][kbl], ao, 0, 0, 0);
            au = MFMA_B16(ax, bX[2][kbl], au, 0, 0, 0);
            awx = MFMA_B16(ax, bX[3][kbl], awx, 0, 0, 0);
        }
#pragma unroll
        for (int r = 0; r < 4; r++) {
            int idx = quad * 4 + r;
            if (idx < nv) {
                int node = base + idx;
                int ch = 2 * node + 1;
                float iv = sig_(ai[r] + bb[0]);
                float ov = sig_(ao[r] + bb[1]);
                float uv = tanh_(au[r] + bb[2]);
                float f0 = sig_(awx[r] + af0[r] + bb[3]);
                float f1 = sig_(awx[r] + af1[r] + bb[4]);
                float c0 = b2f_u(S[HC0 + ch * 136 + o]);
                float c1 = b2f_u(S[HC0 + (ch + 1) * 136 + o]);
                float cn = iv * uv + f0 * c0 + f1 * c1;
                float hn = ov * tanh_(cn);
                S[node * 136 + o] = f2b(hn);
                S[HC0 + node * 136 + o] = f2b(cn);
                if (isRoot) {
                    out[((size_t)l * 128 + tree) * 128 + o] = hn;
                    out[32768 + ((size_t)l * 128 + tree) * 128 + o] = cn;
                }
            }
        }
    };

    // ---- prologue: leaf pair 0 -> buf 0 (rows 63..94) ----
    ltile(255 + l15, 63);
    ltile(271 + l15, 63 + 16);
    BARLDS();

    // ---- leaf/d7 loop: 8 intervals, d7 h/c -> global ----
#pragma unroll 1
    for (int t = 0; t < 8; t++) {
        const int b = t & 1;
        if (t < 7) {
            const int b2 = b ^ 1;
            ltile(287 + 32 * t + l15, 63 + b2 * 32);
            ltile(303 + 32 * t + l15, 63 + b2 * 32 + 16);
        }
        d7g(t, b);
        BARLDS();
    }

    // publish d7 global writes, then d6 reads them
    __threadfence();
    __syncthreads();

    // ---- d6: 4 independent tiles (global children) -> LDS rows 63..126 ----
#pragma unroll 2
    for (int j = 0; j < 4; j++) d6g(j);
    BARLDS();
    // ---- d5 (2 tiles) ----
    itile_l(31, 16, false);
    itile_l(47, 16, false);
    BARLDS();
    // ---- d4..d0 ----
    itile_l(15, 16, false);
    BARLDS();
    itile_l(7, 8, false);
    BARLDS();
    itile_l(3, 4, false);
    BARLDS();
    itile_l(1, 2, false);
    BARLDS();
    itile_l(0, 1, true);
}

extern "C" void kernel_launch(void* const* d_in, const int* in_sizes, int n_in,
                              void* d_out, int out_size, void* d_ws, size_t ws_size,
                              hipStream_t stream) {
    const float* feat = (const float*)d_in[0];
    const float* Wiou = (const float*)d_in[1];
    const float* biou = (const float*)d_in[2];
    const float* Uiou = (const float*)d_in[3];
    const float* Wf   = (const float*)d_in[4];
    const float* bfv  = (const float*)d_in[5];
    const float* Uf   = (const float*)d_in[6];
    float* out = (float*)d_out;

    // ws (bf16 shorts): BgU[131072] BgX[131072] xb16[NN*128=8372224]
    //   hb7[4194304] cb7[4194304] + bp5(f32)[1280]  ~= 34 MB
    unsigned short* BgU = (unsigned short*)d_ws;
    unsigned short* BgX = BgU + (size_t)131072;
    unsigned short* xb16 = BgX + (size_t)131072;
    unsigned short* hb7 = xb16 + (size_t)NN * 128;
    unsigned short* cb7 = hb7 + (size_t)4194304;
    float* bp5 = (float*)(cb7 + (size_t)4194304);

    pack_b<<<5112, 256, 0, stream>>>(Wiou, biou, Uiou, Wf, bfv, Uf, feat,
                                     BgU, BgX, bp5, xb16);
    forest<<<128, 1024, 0, stream>>>(xb16, BgU, BgX, bp5, hb7, cb7, out);
}

// Round 10
// 163.891 us; speedup vs baseline: 2.7466x; 2.7466x over previous
//
#include <hip/hip_runtime.h>
#include <hip/hip_bf16.h>

// TreeLSTM on MI355X — round 22: R14 forest (session best, 90.4 us) + direct
// f32 weight fragments (no weight-pack pass).
// R21 post-mortem: 1024-thr block -> compiler targets 2 blk/CU -> 64-VGPR cap
// -> B fragments lost register residency -> FETCH 330 MB, 366 us. Stop
// fighting the allocator: the 512-thr/128-VGPR/1-blk R14 shape is the one
// that works. This round: forest body is R14 VERBATIM; only the B/bias init
// changes — Uiou/Wiou row-major IS the fragment layout, so fragments load
// straight from the f32 inputs (one-time convert, 32 fragments/thread).
// pack shrinks to pure x->bf16 streaming (~50 MB, ~10 us). 2 dispatches.
// Diagnostic: if total ~105-115, R14's 67-us gap was pack_b; if ~150, it's
// harness overhead.

#define TS 511
#define NT 128
#define NN (NT * TS)   // 65408

typedef __attribute__((ext_vector_type(8))) short short8;
typedef __attribute__((ext_vector_type(4))) float floatx4;

#define MFMA_B16 __builtin_amdgcn_mfma_f32_16x16x32_bf16

// LDS-only barrier: LDS writes visible, global loads NOT drained.
#define BARLDS() do { \
    asm volatile("s_waitcnt lgkmcnt(0)" ::: "memory"); \
    __builtin_amdgcn_s_barrier(); \
    asm volatile("" ::: "memory"); \
} while (0)

__device__ __forceinline__ unsigned short f2b(float f) {
    return __builtin_bit_cast(unsigned short, __float2bfloat16(f));
}
__device__ __forceinline__ float b2f_u(unsigned short u) {
    unsigned v = (unsigned)u << 16;
    return __builtin_bit_cast(float, v);
}
__device__ __forceinline__ float rcp_(float x) { return __builtin_amdgcn_rcpf(x); }
__device__ __forceinline__ float sig_(float x) { return rcp_(1.0f + __expf(-x)); }
__device__ __forceinline__ float tanh_(float x) {
    float a = fabsf(x);
    float t = __expf(-2.0f * a);
    return copysignf((1.0f - t) * rcp_(1.0f + t), x);
}

// ---------------- x -> bf16 conversion only ----------------
__global__ void pack_x(const float* __restrict__ feat, unsigned short* __restrict__ xb) {
    int e = blockIdx.x * 256 + threadIdx.x;    // 0..1046527, 8 elems each
    size_t base = (size_t)e * 8;
    float4 v0 = *(const float4*)(feat + base);
    float4 v1 = *(const float4*)(feat + base + 4);
    short8 r;
    r[0] = (short)f2b(v0.x); r[1] = (short)f2b(v0.y);
    r[2] = (short)f2b(v0.z); r[3] = (short)f2b(v0.w);
    r[4] = (short)f2b(v1.x); r[5] = (short)f2b(v1.y);
    r[6] = (short)f2b(v1.z); r[7] = (short)f2b(v1.w);
    *(short8*)(xb + base) = r;
}

// ---------------- whole-forest kernel (R14 body) ----------------
// LDS (halfwords, row stride 136):
//   h-space rows 0..191: internal ring (d7:0..127, d6:128..191, d5:0..31,
//     d4:32..47, d3:48..55, d2:56..59, d1:60..61, d0:62)
//   c-space rows 0..191 @S[HC0]: same ring
//   leaf h: rows 384+b*32+r (h-space), leaf c: rows 256+b*32+r (c-space)
__global__ __launch_bounds__(512) void forest(
        const unsigned short* __restrict__ xb16,
        const float* __restrict__ Wiou, const float* __restrict__ biou,
        const float* __restrict__ Uiou, const float* __restrict__ Wf,
        const float* __restrict__ bfv, const float* __restrict__ Uf,
        float* __restrict__ out) {
    __shared__ __align__(16) unsigned short S[69632];
    const int HC0 = 26112;

    const int tid = threadIdx.x;
    const int l = blockIdx.x >> 7, tree = blockIdx.x & 127;
    const int lane = tid & 63, w = tid >> 6;
    const int quad = lane >> 4, l15 = lane & 15;
    const int o = w * 16 + l15;
    const unsigned short* xb = xb16 + (size_t)tree * TS * 128;

    auto ldw8 = [&](const float* p) -> short8 {
        float4 u0 = *(const float4*)p;
        float4 u1 = *(const float4*)(p + 4);
        short8 r;
        r[0] = (short)f2b(u0.x); r[1] = (short)f2b(u0.y);
        r[2] = (short)f2b(u0.z); r[3] = (short)f2b(u0.w);
        r[4] = (short)f2b(u1.x); r[5] = (short)f2b(u1.y);
        r[6] = (short)f2b(u1.z); r[7] = (short)f2b(u1.w);
        return r;
    };

    // resident B fragments, read DIRECTLY from f32 weights (row-major weight
    // layout == fragment layout): gates i,o,u,f (f0/f1 share Wf and Uf cols)
    short8 bU[4][4], bX[4][4];
#pragma unroll
    for (int g = 0; g < 4; g++) {
        const float* pU = (g < 3) ? (Uiou + ((size_t)(l * 384 + g * 128 + o)) * 128)
                                  : (Uf + ((size_t)(l * 128 + o)) * 128);
        const float* pX = (g < 3) ? (Wiou + ((size_t)(l * 384 + g * 128 + o)) * 128)
                                  : (Wf + ((size_t)(l * 128 + o)) * 128);
#pragma unroll
        for (int kbl = 0; kbl < 4; kbl++) {
            bU[g][kbl] = ldw8(pU + kbl * 32 + quad * 8);
            bX[g][kbl] = ldw8(pX + kbl * 32 + quad * 8);
        }
    }
    float bb[5];
#pragma unroll
    for (int g = 0; g < 3; g++) bb[g] = biou[l * 384 + g * 128 + o];
    bb[3] = bfv[l * 128 + o];
    bb[4] = bb[3];

    auto ldx = [&](int heap, int kbl) -> short8 {
        return *(const short8*)(xb + (size_t)heap * 128 + kbl * 32 + quad * 8);
    };

    // 16-row leaf tile: x-only gates, h/c -> leaf buffer rows
    auto ltile = [&](int heapA, int selfH, int selfC) {
        floatx4 ai = (floatx4){0.f, 0.f, 0.f, 0.f};
        floatx4 ao = ai, au = ai;
#pragma unroll
        for (int kbl = 0; kbl < 4; kbl++) {
            short8 ax = ldx(heapA, kbl);
            ai = MFMA_B16(ax, bX[0][kbl], ai, 0, 0, 0);
            ao = MFMA_B16(ax, bX[1][kbl], ao, 0, 0, 0);
            au = MFMA_B16(ax, bX[2][kbl], au, 0, 0, 0);
        }
#pragma unroll
        for (int r = 0; r < 4; r++) {
            int idx = quad * 4 + r;
            float iv = sig_(ai[r] + bb[0]);
            float ov = sig_(ao[r] + bb[1]);
            float uv = tanh_(au[r] + bb[2]);
            float cn = iv * uv;
            float hn = ov * tanh_(cn);
            S[(selfH + idx) * 136 + o] = f2b(hn);
            S[HC0 + (selfC + idx) * 136 + o] = f2b(cn);
        }
    };

    // 16-node internal tile. chAh: per-lane child0 h-space row (A-side);
    // chRBc: c-space row base of children; selfRB: own h/c row base.
    auto itile = [&](int heapA, int chAh, int selfRB, int chRBc,
                     int nValid, bool isRoot) {
        floatx4 ai = (floatx4){0.f, 0.f, 0.f, 0.f};
        floatx4 ao = ai, au = ai, awx = ai, af0 = ai, af1 = ai;
#pragma unroll
        for (int kbl = 0; kbl < 4; kbl++) {
            short8 h0 = *(const short8*)&S[chAh * 136 + kbl * 32 + quad * 8];
            short8 h1 = *(const short8*)&S[(chAh + 1) * 136 + kbl * 32 + quad * 8];
            short8 ax = ldx(heapA, kbl);
            ai = MFMA_B16(h0, bU[0][kbl], ai, 0, 0, 0);
            ai = MFMA_B16(h1, bU[0][kbl], ai, 0, 0, 0);
            ao = MFMA_B16(h0, bU[1][kbl], ao, 0, 0, 0);
            ao = MFMA_B16(h1, bU[1][kbl], ao, 0, 0, 0);
            au = MFMA_B16(h0, bU[2][kbl], au, 0, 0, 0);
            au = MFMA_B16(h1, bU[2][kbl], au, 0, 0, 0);
            af0 = MFMA_B16(h0, bU[3][kbl], af0, 0, 0, 0);
            af1 = MFMA_B16(h1, bU[3][kbl], af1, 0, 0, 0);
            ai = MFMA_B16(ax, bX[0][kbl], ai, 0, 0, 0);
            ao = MFMA_B16(ax, bX[1][kbl], ao, 0, 0, 0);
            au = MFMA_B16(ax, bX[2][kbl], au, 0, 0, 0);
            awx = MFMA_B16(ax, bX[3][kbl], awx, 0, 0, 0);
        }
#pragma unroll
        for (int r = 0; r < 4; r++) {
            int idx = quad * 4 + r;
            if (idx < nValid) {
                float iv = sig_(ai[r] + bb[0]);
                float ov = sig_(ao[r] + bb[1]);
                float uv = tanh_(au[r] + bb[2]);
                float f0 = sig_(awx[r] + af0[r] + bb[3]);
                float f1 = sig_(awx[r] + af1[r] + bb[4]);
                float c0 = b2f_u(S[HC0 + (chRBc + 2 * idx) * 136 + o]);
                float c1 = b2f_u(S[HC0 + (chRBc + 2 * idx + 1) * 136 + o]);
                float cn = iv * uv + f0 * c0 + f1 * c1;
                float hn = ov * tanh_(cn);
                S[(selfRB + idx) * 136 + o] = f2b(hn);
                S[HC0 + (selfRB + idx) * 136 + o] = f2b(cn);
                if (isRoot) {
                    out[((size_t)l * 128 + tree) * 128 + o] = hn;
                    out[32768 + ((size_t)l * 128 + tree) * 128 + o] = cn;
                }
            }
        }
    };

    // ---- prologue: leaf pair 0 -> buf 0 ----
    ltile(255 + l15, 384, 256);
    ltile(271 + l15, 400, 272);
    BARLDS();

    // ---- leaf/d7 loop: 8 intervals, ltile(next) overlaps itile(cur) ----
#pragma unroll 2
    for (int t = 0; t < 8; t++) {
        if (t < 7) {
            int b2 = (t + 1) & 1;
            ltile(287 + t * 32 + l15, 384 + b2 * 32, 256 + b2 * 32);
            ltile(303 + t * 32 + l15, 384 + b2 * 32 + 16, 256 + b2 * 32 + 16);
        }
        int b = t & 1;
        itile(127 + t * 16 + l15,        // d7 node rows (heap 127..254)
              384 + b * 32 + 2 * l15,    // child h in leaf buf
              t * 16,                    // own rows: d7 region 0..127
              256 + b * 32,              // child c in leaf buf
              16, false);
        BARLDS();
    }

    // ---- levels d6..d0, state in the LDS ring ----
#pragma unroll
    for (int dd = 6; dd >= 0; dd--) {
        const int nd = 1 << dd;
        const int selfB = (dd == 6) ? 128 : 64 - 2 * nd;
        const int chB = (dd == 6) ? 0 : ((dd == 5) ? 128 : 64 - 4 * nd);
        const int mts = (nd + 15) >> 4;
#pragma unroll
        for (int mt = 0; mt < mts; mt++) {
            int rl = mt * 16 + l15;
            if (rl > nd - 1) rl = nd - 1;        // clamp tiny levels
            int nv = nd - mt * 16;
            if (nv > 16) nv = 16;
            itile(nd - 1 + rl,                   // heap row
                  chB + 2 * rl,                  // child h row
                  selfB + mt * 16,
                  chB + 2 * mt * 16,             // child c row base
                  nv, dd == 0);
        }
        BARLDS();
    }
}

extern "C" void kernel_launch(void* const* d_in, const int* in_sizes, int n_in,
                              void* d_out, int out_size, void* d_ws, size_t ws_size,
                              hipStream_t stream) {
    const float* feat = (const float*)d_in[0];
    const float* Wiou = (const float*)d_in[1];
    const float* biou = (const float*)d_in[2];
    const float* Uiou = (const float*)d_in[3];
    const float* Wf   = (const float*)d_in[4];
    const float* bfv  = (const float*)d_in[5];
    const float* Uf   = (const float*)d_in[6];
    float* out = (float*)d_out;

    // ws: xb16[NN*128] bf16 shorts (~16.7 MB)
    unsigned short* xb16 = (unsigned short*)d_ws;

    pack_x<<<4088, 256, 0, stream>>>(feat, xb16);
    forest<<<256, 512, 0, stream>>>(xb16, Wiou, biou, Uiou, Wf, bfv, Uf, out);
}